// Round 14
// baseline (30.126 us; speedup 1.0000x reference)
//
#include <hip/hip_runtime.h>
#include <hip/hip_bf16.h>
#include <math.h>

#define D     128
#define NT    256            // B*T
#define HD    32
#define LD    32
#define PADW  132            // f32 LDS row pad
#define STW   136            // st row stride in u16 (272 B = 17*16, 16B-aligned)
#define TILES 136            // 16*17/2 upper-incl-diag 8x8 tiles
#define NSLAB (TILES * 64)   // u16 per token in packed D

static __device__ inline unsigned short f2bf(float f) {
    __hip_bfloat16 b = __float2bfloat16(f);
    return *reinterpret_cast<unsigned short*>(&b);
}
static __device__ inline float bf2f(unsigned int u16v) {
    union { unsigned int i; float f; } v;
    v.i = u16v << 16;
    return v.f;
}

union SmemA {                        // z (P1) overlaid with lin (P2+)
    float zt[LD][PADW];              // 16.9 KB
    float lin[2][D];                 // 1 KB
};
union SmemB {                        // pa/pb overlaid with S-transpose buf
    struct { float spa[HD][PADW]; float spb[HD][PADW]; } p;   // 33.8 KB
    unsigned short st[D][STW];                                // 34.8 KB
};

// ---------------------------------------------------------------------------
// K12: one block per token n, 256 threads (8x8 cells/thread: P3 wave-level
// LDS instrs -33% vs R13). Epilogue writes upper-tri 8x8 tiles of
// D = S - S^T only (4.35 MB total). st uses XOR oct-swizzle: the 544B row
// stride would otherwise make transposed reads a 16-way bank conflict.
// ---------------------------------------------------------------------------
__global__ __launch_bounds__(256) void fused_pab_scores(
    const float* __restrict__ z, const float* __restrict__ W1,
    const float* __restrict__ b1, const float* __restrict__ W2,
    unsigned short* __restrict__ Dp)
{
    __shared__ SmemA sa;
    __shared__ SmemB sb;

    const int t = threadIdx.x;
    const int n = blockIdx.x;

    // ---- stage z transposed: 1024 float4, 4/thread ----
    {
        const float4* zsrc = (const float4*)(z + (size_t)n * (D * LD));
        #pragma unroll
        for (int q = 0; q < 4; ++q) {
            int f = t + q * 256;
            float4 v = zsrc[f];
            int i = f >> 3;              // 0..127
            int l = (f & 7) * 4;         // 0..28
            sa.zt[l + 0][i] = v.x; sa.zt[l + 1][i] = v.y;
            sa.zt[l + 2][i] = v.z; sa.zt[l + 3][i] = v.w;
        }
    }

    // ---- W1 row h into VGPRs ----
    const int h   = t & 31;
    const int isl = t >> 5;              // 0..7 (16-i slab for P1)
    float wa[LD], wb[LD];
    #pragma unroll
    for (int k = 0; k < 8; ++k) {
        *(float4*)&wa[k*4] = *(const float4*)&W1[h * 64 + k*4];
        *(float4*)&wb[k*4] = *(const float4*)&W1[h * 64 + 32 + k*4];
    }
    const float bias = b1[h];
    __syncthreads();                     // (1) z staged

    // ---- P1: 16 i's x 1 h per thread, 32 independent fma chains ----
    {
        float a[16], c[16];
        #pragma unroll
        for (int r = 0; r < 16; ++r) { a[r] = bias; c[r] = 0.f; }
        #pragma unroll
        for (int l = 0; l < LD; ++l) {
            float zr[16];
            #pragma unroll
            for (int k = 0; k < 4; ++k)
                *(float4*)&zr[k*4] = *(const float4*)&sa.zt[l][isl * 16 + k*4];
            #pragma unroll
            for (int r = 0; r < 16; ++r) {
                a[r] = fmaf(zr[r], wa[l], a[r]);
                c[r] = fmaf(zr[r], wb[l], c[r]);
            }
        }
        #pragma unroll
        for (int k = 0; k < 4; ++k) {
            *(float4*)&sb.p.spa[h][isl * 16 + k*4] = *(float4*)&a[k*4];
            *(float4*)&sb.p.spb[h][isl * 16 + k*4] = *(float4*)&c[k*4];
        }
    }

    float w2r[HD];                       // uniform -> scalarized
    #pragma unroll
    for (int q = 0; q < HD; ++q) w2r[q] = 0.5f * W2[q];
    __syncthreads();                     // (2) spa/spb ready; zt dead

    // ---- P2 (all 256 threads; overlaps P3, joined at barrier (3)) ----
    {
        const int kind = t >> 7, i2 = t & 127;
        float s = 0.f;
        #pragma unroll
        for (int hq = 0; hq < HD; ++hq) {
            float v = kind ? sb.p.spb[hq][i2] : sb.p.spa[hq][i2];
            s = fmaf(w2r[hq], v, s);
        }
        sa.lin[kind][i2] = s;            // consumed after barrier (3)
    }

    // ---- P3: abs part, 8i x 8j per thread ----
    const int tx = t & 15;               // j-oct
    const int ty = t >> 4;               // i-oct
    float acc[8][8];
    #pragma unroll
    for (int r = 0; r < 8; ++r)
        #pragma unroll
        for (int c = 0; c < 8; ++c) acc[r][c] = 0.f;

    #pragma unroll 2
    for (int hh = 0; hh < HD; ++hh) {
        float ar[8], br[8];
        *(float4*)&ar[0] = *(const float4*)&sb.p.spa[hh][ty * 8];
        *(float4*)&ar[4] = *(const float4*)&sb.p.spa[hh][ty * 8 + 4];
        *(float4*)&br[0] = *(const float4*)&sb.p.spb[hh][tx * 8];
        *(float4*)&br[4] = *(const float4*)&sb.p.spb[hh][tx * 8 + 4];
        const float w = w2r[hh];
        #pragma unroll
        for (int r = 0; r < 8; ++r)
            #pragma unroll
            for (int c = 0; c < 8; ++c)
                acc[r][c] = fmaf(w, fabsf(ar[r] + br[c]), acc[r][c]);
    }
    __syncthreads();                     // (3) P3 reads done; lin visible

    // ---- add linear terms ----
    {
        float cai[8], cbj[8];
        #pragma unroll
        for (int r = 0; r < 8; ++r) cai[r] = sa.lin[0][ty * 8 + r];
        #pragma unroll
        for (int c = 0; c < 8; ++c) cbj[c] = sa.lin[1][tx * 8 + c];
        #pragma unroll
        for (int r = 0; r < 8; ++r)
            #pragma unroll
            for (int c = 0; c < 8; ++c)
                acc[r][c] += cai[r] + cbj[c];
    }

    // ---- S -> st (bf16, XOR oct-swizzled), overlay safe after (3) ----
    {
        const int physW = (tx ^ (ty & 7)) * 8;   // write: row i, i>>3 = ty
        #pragma unroll
        for (int r = 0; r < 8; ++r) {
            unsigned int pk[4];
            #pragma unroll
            for (int k = 0; k < 4; ++k)
                pk[k] = ((unsigned int)f2bf(acc[r][2*k+1]) << 16) | f2bf(acc[r][2*k]);
            *(uint4*)&sb.st[ty * 8 + r][physW] = *(uint4*)pk;
        }
    }
    __syncthreads();                     // (4) S complete

    // ---- upper-tri tiles only: D = acc - S^T, packed write ----
    if (tx >= ty) {
        float sji[8][8];                 // sji[c][r] = S[j=tx*8+c][i=ty*8+r]
        const int physR = (ty ^ (tx & 7)) * 8;   // read row j: j>>3 = tx
        #pragma unroll
        for (int c = 0; c < 8; ++c) {
            uint4 u = *(const uint4*)&sb.st[tx * 8 + c][physR];
            unsigned int xs[4] = {u.x, u.y, u.z, u.w};
            #pragma unroll
            for (int k = 0; k < 4; ++k) {
                sji[c][2*k]   = bf2f(xs[k] & 0xffff);
                sji[c][2*k+1] = bf2f(xs[k] >> 16);
            }
        }
        const int tidx = ty * 16 - (ty * (ty - 1)) / 2 + (tx - ty);
        unsigned short* Dn = Dp + (size_t)n * NSLAB + tidx * 64;
        #pragma unroll
        for (int r = 0; r < 8; ++r) {
            unsigned int pk[4];
            #pragma unroll
            for (int k = 0; k < 4; ++k) {
                unsigned short lo = f2bf(acc[r][2*k]   - sji[2*k][r]);
                unsigned short hi = f2bf(acc[r][2*k+1] - sji[2*k+1][r]);
                pk[k] = ((unsigned int)hi << 16) | lo;
            }
            *(uint4*)&Dn[r * 8] = *(uint4*)pk;
        }
    }
}

// ---------------------------------------------------------------------------
// K3: one block per packed tile (grid 136, 256 thr). Reads its tile for all
// 256 n (uint4, coalesced), reduces in LDS, then each valid cell (j>i)
// emits A[i][j], A[j][i] = (1-sigma)*sigma(wm), and wm both orientations.
// ---------------------------------------------------------------------------
__global__ __launch_bounds__(256) void finalize_tiles(
    const unsigned short* __restrict__ Dp, const float* __restrict__ Wmag,
    float* __restrict__ out)
{
    __shared__ float red[32][72];        // 32 n-groups x 64 cells (+pad)

    const int b = blockIdx.x;            // 0..135
    int tq = 0, base = 0;                // invert b -> (tq, tp), uniform scalar
    while (b >= base + (16 - tq)) { base += 16 - tq; ++tq; }
    const int tp = tq + (b - base);

    const int t = threadIdx.x;
    const int g = t >> 3;                // n-group 0..31 (8 n each)
    const int s = t & 7;                 // tile row

    float a8[8] = {0.f, 0.f, 0.f, 0.f, 0.f, 0.f, 0.f, 0.f};
    #pragma unroll 2
    for (int q = 0; q < 8; ++q) {
        const int nn = g * 8 + q;
        uint4 u = *(const uint4*)&Dp[(size_t)nn * NSLAB + b * 64 + s * 8];
        unsigned int xs[4] = {u.x, u.y, u.z, u.w};
        #pragma unroll
        for (int k = 0; k < 4; ++k) {
            a8[2*k]   += bf2f(xs[k] & 0xffff);
            a8[2*k+1] += bf2f(xs[k] >> 16);
        }
    }
    *(float4*)&red[g][s * 8]     = make_float4(a8[0], a8[1], a8[2], a8[3]);
    *(float4*)&red[g][s * 8 + 4] = make_float4(a8[4], a8[5], a8[6], a8[7]);
    __syncthreads();

    if (t < 64) {
        const int r = t >> 3, c = t & 7;
        float sum = 0.f;
        #pragma unroll 8
        for (int gg = 0; gg < 32; ++gg) sum += red[gg][t];

        const int i = 8 * tq + r;
        const int j = 8 * tp + c;
        if (i == j) {                    // diag cell: owned once (tq==tp, r==c)
            out[i * D + i]         = 0.f;
            out[D * D + i * D + i] = 0.f;
        } else if (j > i) {              // valid cell (all cells if tp>tq)
            float av  = sum * (1.0f / 256.0f);        // mean over n; TAU = 1
            float dir = 1.0f / (1.0f + __expf(-av));
            float wmm = 0.5f * (Wmag[i * D + j] + Wmag[j * D + i]);
            float sw  = 1.0f / (1.0f + __expf(-wmm));
            out[i * D + j]         = dir * sw;          // A[i][j]
            out[j * D + i]         = (1.0f - dir) * sw; // A[j][i] = sigma(-av)*sw
            out[D * D + i * D + j] = wmm;
            out[D * D + j * D + i] = wmm;
        }
        // cells j < i in diag tiles: mirrored by their (c,r) counterpart
    }
}

extern "C" void kernel_launch(void* const* d_in, const int* in_sizes, int n_in,
                              void* d_out, int out_size, void* d_ws, size_t ws_size,
                              hipStream_t stream)
{
    const float* z    = (const float*)d_in[0];   // (4,64,128,32)
    const float* Wmag = (const float*)d_in[1];   // (128,128)
    const float* W1   = (const float*)d_in[2];   // (32,64)
    const float* b1   = (const float*)d_in[3];   // (32,)
    const float* W2   = (const float*)d_in[4];   // (1,32)
    // d_in[5] = b2: cancels in scores - scores^T.

    unsigned short* Dp = (unsigned short*)d_ws;  // packed upper-tri D, 4.35 MB
    float* out = (float*)d_out;

    fused_pab_scores<<<NT, 256, 0, stream>>>(z, W1, b1, W2, Dp);
    finalize_tiles<<<TILES, 256, 0, stream>>>(Dp, Wmag, out);
}

// Round 15
// 29.264 us; speedup vs baseline: 1.0294x; 1.0294x over previous
//
#include <hip/hip_runtime.h>
#include <hip/hip_bf16.h>
#include <math.h>

#define D     128
#define NT    256            // B*T
#define HD    32
#define LD    32
#define PADW  132            // f32 LDS row pad
#define STW   136            // st row stride in u16 (272 B, 16B-aligned)
#define TILES 136            // 16*17/2 upper-incl-diag 8x8 tiles
#define NSLAB (TILES * 64)   // u16 per token in packed D

static __device__ inline unsigned short f2bf(float f) {
    __hip_bfloat16 b = __float2bfloat16(f);
    return *reinterpret_cast<unsigned short*>(&b);
}
static __device__ inline float bf2f(unsigned int u16v) {
    union { unsigned int i; float f; } v;
    v.i = u16v << 16;
    return v.f;
}

union SmemA {                        // z (P1) overlaid with lin (P2+)
    float zt[LD][PADW];              // 16.9 KB
    float lin[2][D];                 // 1 KB
};
union SmemB {                        // pa/pb overlaid with S-transpose buf
    struct { float spa[HD][PADW]; float spb[HD][PADW]; } p;   // 33.8 KB
    unsigned short st[D][STW];                                // 34.8 KB
};

// ---------------------------------------------------------------------------
// K12: one block per token n, 512 threads (R13's occupancy + P3 tiling)
// with R14's packed upper-triangle epilogue (4.35 MB D traffic).
// Thread (ty, tx): i-oct ty = t>>5, j-quad tx = t&31. Its j-strip is half
// of 8x8 tile (ty, jo = tx>>1); packed-write condition jo >= ty.
// st XOR oct-swizzle kills the 16-way transposed-read conflict.
// ---------------------------------------------------------------------------
__global__ __launch_bounds__(512) void fused_pab_scores(
    const float* __restrict__ z, const float* __restrict__ W1,
    const float* __restrict__ b1, const float* __restrict__ W2,
    unsigned short* __restrict__ Dp)
{
    __shared__ SmemA sa;
    __shared__ SmemB sb;

    const int t = threadIdx.x;
    const int n = blockIdx.x;

    // ---- stage z transposed: 1024 float4, 2/thread ----
    {
        const float4* zsrc = (const float4*)(z + (size_t)n * (D * LD));
        #pragma unroll
        for (int q = 0; q < 2; ++q) {
            int f = t + q * 512;
            float4 v = zsrc[f];
            int i = f >> 3;              // 0..127
            int l = (f & 7) * 4;         // 0..28
            sa.zt[l + 0][i] = v.x; sa.zt[l + 1][i] = v.y;
            sa.zt[l + 2][i] = v.z; sa.zt[l + 3][i] = v.w;
        }
    }

    // ---- W1 row h into VGPRs ----
    const int h  = t & 31;
    const int iq = t >> 5;               // 0..15 (i-oct for P1)
    float wa[LD], wb[LD];
    #pragma unroll
    for (int k = 0; k < 8; ++k) {
        *(float4*)&wa[k*4] = *(const float4*)&W1[h * 64 + k*4];
        *(float4*)&wb[k*4] = *(const float4*)&W1[h * 64 + 32 + k*4];
    }
    const float bias = b1[h];
    __syncthreads();                     // (1) z staged

    // ---- P1: 8 i's x 1 h per thread, 16 independent fma chains ----
    {
        float a[8], c[8];
        #pragma unroll
        for (int r = 0; r < 8; ++r) { a[r] = bias; c[r] = 0.f; }
        #pragma unroll
        for (int l = 0; l < LD; ++l) {
            float4 z0 = *(const float4*)&sa.zt[l][iq * 8];
            float4 z1 = *(const float4*)&sa.zt[l][iq * 8 + 4];
            float zr[8] = {z0.x, z0.y, z0.z, z0.w, z1.x, z1.y, z1.z, z1.w};
            #pragma unroll
            for (int r = 0; r < 8; ++r) {
                a[r] = fmaf(zr[r], wa[l], a[r]);
                c[r] = fmaf(zr[r], wb[l], c[r]);
            }
        }
        *(float4*)&sb.p.spa[h][iq * 8]     = make_float4(a[0], a[1], a[2], a[3]);
        *(float4*)&sb.p.spa[h][iq * 8 + 4] = make_float4(a[4], a[5], a[6], a[7]);
        *(float4*)&sb.p.spb[h][iq * 8]     = make_float4(c[0], c[1], c[2], c[3]);
        *(float4*)&sb.p.spb[h][iq * 8 + 4] = make_float4(c[4], c[5], c[6], c[7]);
    }

    float w2r[HD];                       // uniform -> scalarized
    #pragma unroll
    for (int q = 0; q < HD; ++q) w2r[q] = 0.5f * W2[q];
    __syncthreads();                     // (2) spa/spb ready; zt dead

    // ---- P2 (t<256 only; overlaps P3, joined at barrier (3)) ----
    if (t < 256) {
        const int kind = t >> 7, i2 = t & 127;
        float s = 0.f;
        #pragma unroll
        for (int hq = 0; hq < HD; ++hq) {
            float v = kind ? sb.p.spb[hq][i2] : sb.p.spa[hq][i2];
            s = fmaf(w2r[hq], v, s);
        }
        sa.lin[kind][i2] = s;            // consumed after barrier (3)
    }

    // ---- P3: abs part, 8i x 4j per thread ----
    const int tx = t & 31;               // j-quad
    const int ty = t >> 5;               // i-oct
    float acc[8][4];
    #pragma unroll
    for (int r = 0; r < 8; ++r)
        #pragma unroll
        for (int c = 0; c < 4; ++c) acc[r][c] = 0.f;

    #pragma unroll 4
    for (int hh = 0; hh < HD; ++hh) {
        float4 a0 = *(const float4*)&sb.p.spa[hh][ty * 8];
        float4 a1 = *(const float4*)&sb.p.spa[hh][ty * 8 + 4];
        float4 bv = *(const float4*)&sb.p.spb[hh][tx * 4];
        const float w = w2r[hh];
        float ar[8] = {a0.x, a0.y, a0.z, a0.w, a1.x, a1.y, a1.z, a1.w};
        float br[4] = {bv.x, bv.y, bv.z, bv.w};
        #pragma unroll
        for (int r = 0; r < 8; ++r)
            #pragma unroll
            for (int c = 0; c < 4; ++c)
                acc[r][c] = fmaf(w, fabsf(ar[r] + br[c]), acc[r][c]);
    }
    __syncthreads();                     // (3) P3/P2 reads done; lin visible

    // ---- add linear terms ----
    {
        float cai[8], cbj[4];
        #pragma unroll
        for (int r = 0; r < 8; ++r) cai[r] = sa.lin[0][ty * 8 + r];
        #pragma unroll
        for (int c = 0; c < 4; ++c) cbj[c] = sa.lin[1][tx * 4 + c];
        #pragma unroll
        for (int r = 0; r < 8; ++r)
            #pragma unroll
            for (int c = 0; c < 4; ++c)
                acc[r][c] += cai[r] + cbj[c];
    }

    // ---- S -> st (bf16, XOR oct-swizzled), overlay safe after (3) ----
    const int jo = tx >> 1;              // j-oct 0..15
    const int jh = tx & 1;               // half within oct
    {
        const int physW = ((jo ^ (ty & 7)) * 8) + jh * 4;
        #pragma unroll
        for (int r = 0; r < 8; ++r) {
            unsigned int p0 = ((unsigned int)f2bf(acc[r][1]) << 16) | f2bf(acc[r][0]);
            unsigned int p1 = ((unsigned int)f2bf(acc[r][3]) << 16) | f2bf(acc[r][2]);
            *(uint2*)&sb.st[ty * 8 + r][physW] = make_uint2(p0, p1);
        }
    }
    __syncthreads();                     // (4) S complete

    // ---- upper-tri tiles only: D = acc - S^T, packed write ----
    if (jo >= ty) {
        float sji[4][8];                 // sji[c][r] = S[j][i=ty*8+r]
        const int physR = (ty ^ (jo & 7)) * 8;
        #pragma unroll
        for (int c = 0; c < 4; ++c) {
            const int j = jo * 8 + jh * 4 + c;
            uint4 u = *(const uint4*)&sb.st[j][physR];
            unsigned int xs[4] = {u.x, u.y, u.z, u.w};
            #pragma unroll
            for (int k = 0; k < 4; ++k) {
                sji[c][2*k]   = bf2f(xs[k] & 0xffff);
                sji[c][2*k+1] = bf2f(xs[k] >> 16);
            }
        }
        const int tidx = ty * 16 - (ty * (ty - 1)) / 2 + (jo - ty);
        unsigned short* Dn = Dp + (size_t)n * NSLAB + tidx * 64;
        #pragma unroll
        for (int r = 0; r < 8; ++r) {
            unsigned short l0 = f2bf(acc[r][0] - sji[0][r]);
            unsigned short l1 = f2bf(acc[r][1] - sji[1][r]);
            unsigned short l2 = f2bf(acc[r][2] - sji[2][r]);
            unsigned short l3 = f2bf(acc[r][3] - sji[3][r]);
            unsigned int p0 = ((unsigned int)l1 << 16) | l0;
            unsigned int p1 = ((unsigned int)l3 << 16) | l2;
            *(uint2*)&Dn[r * 8 + jh * 4] = make_uint2(p0, p1);
        }
    }
}

// ---------------------------------------------------------------------------
// K3: one block per packed tile (grid 136, 256 thr). Reads its tile for all
// 256 n (uint4, coalesced), reduces in LDS, then each valid cell (j>i)
// emits A[i][j], A[j][i] = (1-sigma)*sigma(wm), and wm both orientations.
// ---------------------------------------------------------------------------
__global__ __launch_bounds__(256) void finalize_tiles(
    const unsigned short* __restrict__ Dp, const float* __restrict__ Wmag,
    float* __restrict__ out)
{
    __shared__ float red[32][72];        // 32 n-groups x 64 cells (+pad)

    const int b = blockIdx.x;            // 0..135
    int tq = 0, base = 0;                // invert b -> (tq, tp), uniform scalar
    while (b >= base + (16 - tq)) { base += 16 - tq; ++tq; }
    const int tp = tq + (b - base);

    const int t = threadIdx.x;
    const int g = t >> 3;                // n-group 0..31 (8 n each)
    const int s = t & 7;                 // tile row

    float a8[8] = {0.f, 0.f, 0.f, 0.f, 0.f, 0.f, 0.f, 0.f};
    #pragma unroll 2
    for (int q = 0; q < 8; ++q) {
        const int nn = g * 8 + q;
        uint4 u = *(const uint4*)&Dp[(size_t)nn * NSLAB + b * 64 + s * 8];
        unsigned int xs[4] = {u.x, u.y, u.z, u.w};
        #pragma unroll
        for (int k = 0; k < 4; ++k) {
            a8[2*k]   += bf2f(xs[k] & 0xffff);
            a8[2*k+1] += bf2f(xs[k] >> 16);
        }
    }
    *(float4*)&red[g][s * 8]     = make_float4(a8[0], a8[1], a8[2], a8[3]);
    *(float4*)&red[g][s * 8 + 4] = make_float4(a8[4], a8[5], a8[6], a8[7]);
    __syncthreads();

    if (t < 64) {
        const int r = t >> 3, c = t & 7;
        float sum = 0.f;
        #pragma unroll 8
        for (int gg = 0; gg < 32; ++gg) sum += red[gg][t];

        const int i = 8 * tq + r;
        const int j = 8 * tp + c;
        if (i == j) {                    // diag cell: owned once (tq==tp, r==c)
            out[i * D + i]         = 0.f;
            out[D * D + i * D + i] = 0.f;
        } else if (j > i) {              // valid cell (all cells if tp>tq)
            float av  = sum * (1.0f / 256.0f);        // mean over n; TAU = 1
            float dir = 1.0f / (1.0f + __expf(-av));
            float wmm = 0.5f * (Wmag[i * D + j] + Wmag[j * D + i]);
            float sw  = 1.0f / (1.0f + __expf(-wmm));
            out[i * D + j]         = dir * sw;          // A[i][j]
            out[j * D + i]         = (1.0f - dir) * sw; // A[j][i] = sigma(-av)*sw
            out[D * D + i * D + j] = wmm;
            out[D * D + j * D + i] = wmm;
        }
        // cells j < i in diag tiles: mirrored by their (c,r) counterpart
    }
}

extern "C" void kernel_launch(void* const* d_in, const int* in_sizes, int n_in,
                              void* d_out, int out_size, void* d_ws, size_t ws_size,
                              hipStream_t stream)
{
    const float* z    = (const float*)d_in[0];   // (4,64,128,32)
    const float* Wmag = (const float*)d_in[1];   // (128,128)
    const float* W1   = (const float*)d_in[2];   // (32,64)
    const float* b1   = (const float*)d_in[3];   // (32,)
    const float* W2   = (const float*)d_in[4];   // (1,32)
    // d_in[5] = b2: cancels in scores - scores^T.

    unsigned short* Dp = (unsigned short*)d_ws;  // packed upper-tri D, 4.35 MB
    float* out = (float*)d_out;

    fused_pab_scores<<<NT, 512, 0, stream>>>(z, W1, b1, W2, Dp);
    finalize_tiles<<<TILES, 256, 0, stream>>>(Dp, Wmag, out);
}

// Round 16
// 28.193 us; speedup vs baseline: 1.0686x; 1.0380x over previous
//
#include <hip/hip_runtime.h>
#include <hip/hip_bf16.h>
#include <math.h>

#define D     128
#define NT    256            // B*T
#define HD    32
#define LD    32
#define P32   132            // u32-row pad for fp16-pair tiles
#define STW   136            // st row stride in u16 (272 B, 16B-aligned)
#define TILES 136            // 16*17/2 upper-incl-diag 8x8 tiles
#define NSLAB (TILES * 64)   // u16 per token in packed D

typedef _Float16 h2v __attribute__((ext_vector_type(2)));

static __device__ inline unsigned short f2bf(float f) {
    __hip_bfloat16 b = __float2bfloat16(f);
    return *reinterpret_cast<unsigned short*>(&b);
}
static __device__ inline float bf2f(unsigned int u16v) {
    union { unsigned int i; float f; } v;
    v.i = u16v << 16;
    return v.f;
}
// RNE fp16 pair pack (v_cvt_f16_f32 x2 + v_pack); only outside hot loops
static __device__ inline unsigned int pkh2(float a, float b) {
    union { h2v h; unsigned int u; } cv;
    cv.h = (h2v){(_Float16)a, (_Float16)b};
    return cv.u;
}
static __device__ inline h2v u2h(unsigned int u) {
    union { unsigned int u; h2v h; } cv; cv.u = u; return cv.h;
}
static __device__ inline float fdot2f(h2v a, h2v b, float c) {
#if __has_builtin(__builtin_amdgcn_fdot2)
    return __builtin_amdgcn_fdot2(a, b, c, false);
#else
    return c + (float)a[0] * (float)b[0] + (float)a[1] * (float)b[1];
#endif
}

union SmemA {                        // z16 (P1) overlaid with lin (P2+)
    unsigned int zt[16][P32];        // fp16 l-pairs of z, transposed: 8.4 KB
    float lin[2][D];                 // 1 KB
};
union SmemB {                        // fp16-pair pa/pb overlaid with st buf
    struct { unsigned int a[16][P32]; unsigned int b[16][P32]; } p;  // 16.9 KB
    unsigned short st[D][STW];                                       // 34.8 KB
};

// ---------------------------------------------------------------------------
// K12: one block per token n, 512 threads. fp16-pair datapath:
//  P1: pa/pb via fdot2 (z,W1 fp16 pairs; f32 accumulate) -> LDS fp16 h-pairs.
//  P2: rank-1 relu-split terms via fdot2 (f32).
//  P3: per (cell, h-pair): v_pk_add_f16 + v_and(|.|x2) + v_dot2_f32_f16
//      = 3 VALU per 2 h (vs 4 scalar); LDS reads halved.
//  epilogue: R15's bf16 st-transpose + packed upper-tri D (4.35 MB).
// ---------------------------------------------------------------------------
__global__ __launch_bounds__(512) void fused_pab_scores(
    const float* __restrict__ z, const float* __restrict__ W1,
    const float* __restrict__ b1, const float* __restrict__ W2,
    unsigned short* __restrict__ Dp)
{
    __shared__ SmemA sa;
    __shared__ SmemB sb;

    const int t = threadIdx.x;
    const int n = blockIdx.x;

    // ---- stage z transposed as fp16 l-pairs: 1024 float4, 2/thread ----
    {
        const float4* zsrc = (const float4*)(z + (size_t)n * (D * LD));
        #pragma unroll
        for (int q = 0; q < 2; ++q) {
            int f = t + q * 512;
            float4 v = zsrc[f];
            int i  = f >> 3;             // 0..127
            int l2 = (f & 7) * 2;        // l-pair index 0..14 (step 2)
            sa.zt[l2][i]     = pkh2(v.x, v.y);
            sa.zt[l2 + 1][i] = pkh2(v.z, v.w);
        }
    }

    // ---- W1 rows (h-pair) as fp16 l-pairs in VGPRs ----
    const int h2i = t & 15;              // h-pair 0..15
    const int iq  = t >> 4;              // i-quad 0..31
    const int h0 = 2 * h2i, h1 = h0 + 1;
    unsigned int wpkA0[16], wpkA1[16], wpkB0[16], wpkB1[16];
    {
        const float* w1r0 = &W1[h0 * 64];
        const float* w1r1 = &W1[h1 * 64];
        #pragma unroll
        for (int l2 = 0; l2 < 16; ++l2) {
            wpkA0[l2] = pkh2(w1r0[2*l2],      w1r0[2*l2 + 1]);
            wpkB0[l2] = pkh2(w1r0[32 + 2*l2], w1r0[32 + 2*l2 + 1]);
            wpkA1[l2] = pkh2(w1r1[2*l2],      w1r1[2*l2 + 1]);
            wpkB1[l2] = pkh2(w1r1[32 + 2*l2], w1r1[32 + 2*l2 + 1]);
        }
    }
    const float bias0 = b1[h0], bias1 = b1[h1];

    unsigned int w2pk[16];               // (w2[2q]/2, w2[2q+1]/2) fp16 pairs
    #pragma unroll
    for (int q = 0; q < 16; ++q)
        w2pk[q] = pkh2(0.5f * W2[2*q], 0.5f * W2[2*q + 1]);
    __syncthreads();                     // (1) z staged

    // ---- P1: 4 i's x (h0,h1) x (a,b) = 16 f32 accs over 16 fdot2 ----
    {
        float A0[4], A1[4], B0[4], B1[4];
        #pragma unroll
        for (int r = 0; r < 4; ++r) { A0[r] = bias0; A1[r] = bias1; B0[r] = 0.f; B1[r] = 0.f; }
        #pragma unroll
        for (int l2 = 0; l2 < 16; ++l2) {
            unsigned int zq[4];
            *(uint4*)zq = *(const uint4*)&sa.zt[l2][iq * 4];
            #pragma unroll
            for (int r = 0; r < 4; ++r) {
                h2v zv = u2h(zq[r]);
                A0[r] = fdot2f(zv, u2h(wpkA0[l2]), A0[r]);
                A1[r] = fdot2f(zv, u2h(wpkA1[l2]), A1[r]);
                B0[r] = fdot2f(zv, u2h(wpkB0[l2]), B0[r]);
                B1[r] = fdot2f(zv, u2h(wpkB1[l2]), B1[r]);
            }
        }
        unsigned int pa4[4], pb4[4];
        #pragma unroll
        for (int r = 0; r < 4; ++r) {
            pa4[r] = pkh2(A0[r], A1[r]);     // pack across h-pair
            pb4[r] = pkh2(B0[r], B1[r]);
        }
        *(uint4*)&sb.p.a[h2i][iq * 4] = *(uint4*)pa4;
        *(uint4*)&sb.p.b[h2i][iq * 4] = *(uint4*)pb4;
    }
    __syncthreads();                     // (2) fp16 pa/pb ready; zt dead

    // ---- P2 (t<256; overlaps P3, joined at barrier (3)) ----
    if (t < 256) {
        const int kind = t >> 7, i2 = t & 127;
        float s = 0.f;
        #pragma unroll
        for (int q = 0; q < 16; ++q) {
            unsigned int v = kind ? sb.p.b[q][i2] : sb.p.a[q][i2];
            s = fdot2f(u2h(v), u2h(w2pk[q]), s);
        }
        sa.lin[kind][i2] = s;            // consumed after barrier (3)
    }

    // ---- P3: abs part, 8i x 4j per thread, fp16-pair datapath ----
    const int tx = t & 31;               // j-quad
    const int ty = t >> 5;               // i-oct
    float acc[8][4];
    #pragma unroll
    for (int r = 0; r < 8; ++r)
        #pragma unroll
        for (int c = 0; c < 4; ++c) acc[r][c] = 0.f;

    #pragma unroll 4
    for (int q = 0; q < 16; ++q) {
        unsigned int a8[8], b4[4];
        *(uint4*)&a8[0] = *(const uint4*)&sb.p.a[q][ty * 8];
        *(uint4*)&a8[4] = *(const uint4*)&sb.p.a[q][ty * 8 + 4];
        *(uint4*)&b4[0] = *(const uint4*)&sb.p.b[q][tx * 4];
        const h2v w = u2h(w2pk[q]);
        #pragma unroll
        for (int r = 0; r < 8; ++r) {
            const h2v ha = u2h(a8[r]);
            #pragma unroll
            for (int c = 0; c < 4; ++c) {
                union { h2v h; unsigned int u; } cv;
                cv.h = ha + u2h(b4[c]);              // v_pk_add_f16
                cv.u &= 0x7fff7fffu;                 // |.| both halves
                acc[r][c] = fdot2f(cv.h, w, acc[r][c]);
            }
        }
    }
    __syncthreads();                     // (3) P3/P2 reads done; lin visible

    // ---- add linear terms ----
    {
        float cai[8], cbj[4];
        #pragma unroll
        for (int r = 0; r < 8; ++r) cai[r] = sa.lin[0][ty * 8 + r];
        #pragma unroll
        for (int c = 0; c < 4; ++c) cbj[c] = sa.lin[1][tx * 4 + c];
        #pragma unroll
        for (int r = 0; r < 8; ++r)
            #pragma unroll
            for (int c = 0; c < 4; ++c)
                acc[r][c] += cai[r] + cbj[c];
    }

    // ---- S -> st (bf16, XOR oct-swizzled), overlay safe after (3) ----
    const int jo = tx >> 1;              // j-oct 0..15
    const int jh = tx & 1;               // half within oct
    {
        const int physW = ((jo ^ (ty & 7)) * 8) + jh * 4;
        #pragma unroll
        for (int r = 0; r < 8; ++r) {
            unsigned int p0 = ((unsigned int)f2bf(acc[r][1]) << 16) | f2bf(acc[r][0]);
            unsigned int p1 = ((unsigned int)f2bf(acc[r][3]) << 16) | f2bf(acc[r][2]);
            *(uint2*)&sb.st[ty * 8 + r][physW] = make_uint2(p0, p1);
        }
    }
    __syncthreads();                     // (4) S complete

    // ---- upper-tri tiles only: D = acc - S^T, packed write ----
    if (jo >= ty) {
        float sji[4][8];                 // sji[c][r] = S[j][i=ty*8+r]
        const int physR = (ty ^ (jo & 7)) * 8;
        #pragma unroll
        for (int c = 0; c < 4; ++c) {
            const int j = jo * 8 + jh * 4 + c;
            uint4 u = *(const uint4*)&sb.st[j][physR];
            unsigned int xs[4] = {u.x, u.y, u.z, u.w};
            #pragma unroll
            for (int k = 0; k < 4; ++k) {
                sji[c][2*k]   = bf2f(xs[k] & 0xffff);
                sji[c][2*k+1] = bf2f(xs[k] >> 16);
            }
        }
        const int tidx = ty * 16 - (ty * (ty - 1)) / 2 + (jo - ty);
        unsigned short* Dn = Dp + (size_t)n * NSLAB + tidx * 64;
        #pragma unroll
        for (int r = 0; r < 8; ++r) {
            unsigned short l0 = f2bf(acc[r][0] - sji[0][r]);
            unsigned short l1 = f2bf(acc[r][1] - sji[1][r]);
            unsigned short l2 = f2bf(acc[r][2] - sji[2][r]);
            unsigned short l3 = f2bf(acc[r][3] - sji[3][r]);
            unsigned int p0 = ((unsigned int)l1 << 16) | l0;
            unsigned int p1 = ((unsigned int)l3 << 16) | l2;
            *(uint2*)&Dn[r * 8 + jh * 4] = make_uint2(p0, p1);
        }
    }
}

// ---------------------------------------------------------------------------
// K3: one block per packed tile (grid 136, 256 thr). Reads its tile for all
// 256 n (uint4, coalesced), reduces in LDS, then each valid cell (j>i)
// emits A[i][j], A[j][i] = (1-sigma)*sigma(wm), and wm both orientations.
// ---------------------------------------------------------------------------
__global__ __launch_bounds__(256) void finalize_tiles(
    const unsigned short* __restrict__ Dp, const float* __restrict__ Wmag,
    float* __restrict__ out)
{
    __shared__ float red[32][72];        // 32 n-groups x 64 cells (+pad)

    const int b = blockIdx.x;            // 0..135
    int tq = 0, base = 0;                // invert b -> (tq, tp), uniform scalar
    while (b >= base + (16 - tq)) { base += 16 - tq; ++tq; }
    const int tp = tq + (b - base);

    const int t = threadIdx.x;
    const int g = t >> 3;                // n-group 0..31 (8 n each)
    const int s = t & 7;                 // tile row

    float a8[8] = {0.f, 0.f, 0.f, 0.f, 0.f, 0.f, 0.f, 0.f};
    #pragma unroll 2
    for (int q = 0; q < 8; ++q) {
        const int nn = g * 8 + q;
        uint4 u = *(const uint4*)&Dp[(size_t)nn * NSLAB + b * 64 + s * 8];
        unsigned int xs[4] = {u.x, u.y, u.z, u.w};
        #pragma unroll
        for (int k = 0; k < 4; ++k) {
            a8[2*k]   += bf2f(xs[k] & 0xffff);
            a8[2*k+1] += bf2f(xs[k] >> 16);
        }
    }
    *(float4*)&red[g][s * 8]     = make_float4(a8[0], a8[1], a8[2], a8[3]);
    *(float4*)&red[g][s * 8 + 4] = make_float4(a8[4], a8[5], a8[6], a8[7]);
    __syncthreads();

    if (t < 64) {
        const int r = t >> 3, c = t & 7;
        float sum = 0.f;
        #pragma unroll 8
        for (int gg = 0; gg < 32; ++gg) sum += red[gg][t];

        const int i = 8 * tq + r;
        const int j = 8 * tp + c;
        if (i == j) {                    // diag cell: owned once (tq==tp, r==c)
            out[i * D + i]         = 0.f;
            out[D * D + i * D + i] = 0.f;
        } else if (j > i) {              // valid cell (all cells if tp>tq)
            float av  = sum * (1.0f / 256.0f);        // mean over n; TAU = 1
            float dir = 1.0f / (1.0f + __expf(-av));
            float wmm = 0.5f * (Wmag[i * D + j] + Wmag[j * D + i]);
            float sw  = 1.0f / (1.0f + __expf(-wmm));
            out[i * D + j]         = dir * sw;          // A[i][j]
            out[j * D + i]         = (1.0f - dir) * sw; // A[j][i] = sigma(-av)*sw
            out[D * D + i * D + j] = wmm;
            out[D * D + j * D + i] = wmm;
        }
        // cells j < i in diag tiles: mirrored by their (c,r) counterpart
    }
}

extern "C" void kernel_launch(void* const* d_in, const int* in_sizes, int n_in,
                              void* d_out, int out_size, void* d_ws, size_t ws_size,
                              hipStream_t stream)
{
    const float* z    = (const float*)d_in[0];   // (4,64,128,32)
    const float* Wmag = (const float*)d_in[1];   // (128,128)
    const float* W1   = (const float*)d_in[2];   // (32,64)
    const float* b1   = (const float*)d_in[3];   // (32,)
    const float* W2   = (const float*)d_in[4];   // (1,32)
    // d_in[5] = b2: cancels in scores - scores^T.

    unsigned short* Dp = (unsigned short*)d_ws;  // packed upper-tri D, 4.35 MB
    float* out = (float*)d_out;

    fused_pab_scores<<<NT, 512, 0, stream>>>(z, W1, b1, W2, Dp);
    finalize_tiles<<<TILES, 256, 0, stream>>>(Dp, Wmag, out);
}

// Round 17
// 25.215 us; speedup vs baseline: 1.1947x; 1.1181x over previous
//
#include <hip/hip_runtime.h>
#include <hip/hip_bf16.h>
#include <math.h>

#define D     128
#define NT    256            // B*T
#define HD    32
#define LD    32
#define P32   132            // u32-row pad for fp16-pair tiles
#define STW   136            // st row stride in u16 (272 B, 16B-aligned)
#define TILES 136            // 16*17/2 upper-incl-diag 8x8 tiles
#define NSLAB (TILES * 64)   // u16 per token in packed D

typedef _Float16 h2v __attribute__((ext_vector_type(2)));

static __device__ inline float bf2f(unsigned int u16v) {
    union { unsigned int i; float f; } v;
    v.i = u16v << 16;
    return v.f;
}
// RNE fp16 pair pack; only outside hot loops
static __device__ inline unsigned int pkh2(float a, float b) {
    union { h2v h; unsigned int u; } cv;
    cv.h = (h2v){(_Float16)a, (_Float16)b};
    return cv.u;
}
static __device__ inline h2v u2h(unsigned int u) {
    union { unsigned int u; h2v h; } cv; cv.u = u; return cv.h;
}
static __device__ inline float fdot2f(h2v a, h2v b, float c) {
#if __has_builtin(__builtin_amdgcn_fdot2)
    return __builtin_amdgcn_fdot2(a, b, c, false);
#else
    return c + (float)a[0] * (float)b[0] + (float)a[1] * (float)b[1];
#endif
}
// 2x f32 -> packed bf16 pair (RNE), single instruction on gfx950
static __device__ inline unsigned int cvtpk_bf16(float lo, float hi) {
    unsigned int r;
    asm("v_cvt_pk_bf16_f32 %0, %1, %2" : "=v"(r) : "v"(lo), "v"(hi));
    return r;
}

union SmemA {                        // staging (P1) overlaid with lin (P2+)
    struct {
        unsigned int zt[16][P32];    // fp16 l-pairs of z, transposed: 8.4 KB
        unsigned int w1pk[32][36];   // fp16 l-pairs of W1 rows: 4.6 KB
        unsigned int w2p[16];        // fp16 h-pairs of w2/2: 64 B
    } s;
    float lin[2][D];                 // rank-1 relu-split terms, 1 KB
};
union SmemB {                        // fp16-pair pa/pb overlaid with st buf
    struct { unsigned int a[16][P32]; unsigned int b[16][P32]; } p;  // 16.9 KB
    unsigned short st[D][STW];                                       // 34.8 KB
};

// ---------------------------------------------------------------------------
// K12: one block per token n, 512 threads. vs R16: W1/w2 fp16 packing done
// cooperatively in LDS (was ~280 redundant VALU/thread), epilogue bf16
// packing via v_cvt_pk_bf16_f32 (1 instr vs ~7). P1/P2/P3 datapath and the
// packed upper-tri D epilogue unchanged.
// ---------------------------------------------------------------------------
__global__ __launch_bounds__(512) void fused_pab_scores(
    const float* __restrict__ z, const float* __restrict__ W1,
    const float* __restrict__ b1, const float* __restrict__ W2,
    unsigned short* __restrict__ Dp)
{
    __shared__ SmemA sa;
    __shared__ SmemB sb;

    const int t = threadIdx.x;
    const int n = blockIdx.x;

    // ---- stage z transposed as fp16 l-pairs: 1024 float4, 2/thread ----
    {
        const float4* zsrc = (const float4*)(z + (size_t)n * (D * LD));
        #pragma unroll
        for (int q = 0; q < 2; ++q) {
            int f = t + q * 512;
            float4 v = zsrc[f];
            int i  = f >> 3;             // 0..127
            int l2 = (f & 7) * 2;        // l-pair index
            sa.s.zt[l2][i]     = pkh2(v.x, v.y);
            sa.s.zt[l2 + 1][i] = pkh2(v.z, v.w);
        }
    }
    // ---- stage W1 packed cooperatively: 1024 u32, 2/thread ----
    {
        #pragma unroll
        for (int q = 0; q < 2; ++q) {
            int u = t + q * 512;         // 0..1023
            float2 w = *(const float2*)&W1[2 * u];
            sa.s.w1pk[u >> 5][u & 31] = pkh2(w.x, w.y);
        }
    }
    if (t < 16)
        sa.s.w2p[t] = pkh2(0.5f * W2[2 * t], 0.5f * W2[2 * t + 1]);

    const int h2i = t & 15;              // h-pair 0..15
    const int iq  = t >> 4;              // i-quad 0..31
    const int h0 = 2 * h2i, h1 = h0 + 1;
    const float bias0 = b1[h0], bias1 = b1[h1];
    __syncthreads();                     // (1) z/W1/w2 staged

    // ---- read back packed W1 rows + w2 (broadcast-friendly b128) ----
    unsigned int wpkA0[16], wpkA1[16], wpkB0[16], wpkB1[16], w2pk[16];
    #pragma unroll
    for (int k = 0; k < 4; ++k) {
        *(uint4*)&wpkA0[4*k] = *(const uint4*)&sa.s.w1pk[h0][4*k];
        *(uint4*)&wpkB0[4*k] = *(const uint4*)&sa.s.w1pk[h0][16 + 4*k];
        *(uint4*)&wpkA1[4*k] = *(const uint4*)&sa.s.w1pk[h1][4*k];
        *(uint4*)&wpkB1[4*k] = *(const uint4*)&sa.s.w1pk[h1][16 + 4*k];
        *(uint4*)&w2pk[4*k]  = *(const uint4*)&sa.s.w2p[4*k];
    }

    // ---- P1: 4 i's x (h0,h1) x (a,b) = 16 f32 accs over 16 fdot2 ----
    {
        float A0[4], A1[4], B0[4], B1[4];
        #pragma unroll
        for (int r = 0; r < 4; ++r) { A0[r] = bias0; A1[r] = bias1; B0[r] = 0.f; B1[r] = 0.f; }
        #pragma unroll
        for (int l2 = 0; l2 < 16; ++l2) {
            unsigned int zq[4];
            *(uint4*)zq = *(const uint4*)&sa.s.zt[l2][iq * 4];
            #pragma unroll
            for (int r = 0; r < 4; ++r) {
                h2v zv = u2h(zq[r]);
                A0[r] = fdot2f(zv, u2h(wpkA0[l2]), A0[r]);
                A1[r] = fdot2f(zv, u2h(wpkA1[l2]), A1[r]);
                B0[r] = fdot2f(zv, u2h(wpkB0[l2]), B0[r]);
                B1[r] = fdot2f(zv, u2h(wpkB1[l2]), B1[r]);
            }
        }
        unsigned int pa4[4], pb4[4];
        #pragma unroll
        for (int r = 0; r < 4; ++r) {
            pa4[r] = pkh2(A0[r], A1[r]);     // pack across h-pair
            pb4[r] = pkh2(B0[r], B1[r]);
        }
        *(uint4*)&sb.p.a[h2i][iq * 4] = *(uint4*)pa4;
        *(uint4*)&sb.p.b[h2i][iq * 4] = *(uint4*)pb4;
    }
    __syncthreads();                     // (2) fp16 pa/pb ready; staging dead

    // ---- P2 (t<256; overlaps P3, joined at barrier (3)) ----
    if (t < 256) {
        const int kind = t >> 7, i2 = t & 127;
        float s = 0.f;
        #pragma unroll
        for (int q = 0; q < 16; ++q) {
            unsigned int v = kind ? sb.p.b[q][i2] : sb.p.a[q][i2];
            s = fdot2f(u2h(v), u2h(w2pk[q]), s);
        }
        sa.lin[kind][i2] = s;            // consumed after barrier (3)
    }

    // ---- P3: abs part, 8i x 4j per thread, fp16-pair datapath ----
    const int tx = t & 31;               // j-quad
    const int ty = t >> 5;               // i-oct
    float acc[8][4];
    #pragma unroll
    for (int r = 0; r < 8; ++r)
        #pragma unroll
        for (int c = 0; c < 4; ++c) acc[r][c] = 0.f;

    #pragma unroll 4
    for (int q = 0; q < 16; ++q) {
        unsigned int a8[8], b4[4];
        *(uint4*)&a8[0] = *(const uint4*)&sb.p.a[q][ty * 8];
        *(uint4*)&a8[4] = *(const uint4*)&sb.p.a[q][ty * 8 + 4];
        *(uint4*)&b4[0] = *(const uint4*)&sb.p.b[q][tx * 4];
        const h2v w = u2h(w2pk[q]);
        #pragma unroll
        for (int r = 0; r < 8; ++r) {
            const h2v ha = u2h(a8[r]);
            #pragma unroll
            for (int c = 0; c < 4; ++c) {
                union { h2v h; unsigned int u; } cv;
                cv.h = ha + u2h(b4[c]);              // v_pk_add_f16
                cv.u &= 0x7fff7fffu;                 // |.| both halves
                acc[r][c] = fdot2f(cv.h, w, acc[r][c]);
            }
        }
    }
    __syncthreads();                     // (3) P3/P2 reads done; lin visible

    // ---- add linear terms ----
    {
        float cai[8], cbj[4];
        #pragma unroll
        for (int r = 0; r < 8; ++r) cai[r] = sa.lin[0][ty * 8 + r];
        #pragma unroll
        for (int c = 0; c < 4; ++c) cbj[c] = sa.lin[1][tx * 4 + c];
        #pragma unroll
        for (int r = 0; r < 8; ++r)
            #pragma unroll
            for (int c = 0; c < 4; ++c)
                acc[r][c] += cai[r] + cbj[c];
    }

    // ---- S -> st (bf16 via cvt_pk, XOR oct-swizzled) ----
    const int jo = tx >> 1;              // j-oct 0..15
    const int jh = tx & 1;               // half within oct
    {
        const int physW = ((jo ^ (ty & 7)) * 8) + jh * 4;
        #pragma unroll
        for (int r = 0; r < 8; ++r) {
            unsigned int p0 = cvtpk_bf16(acc[r][0], acc[r][1]);
            unsigned int p1 = cvtpk_bf16(acc[r][2], acc[r][3]);
            *(uint2*)&sb.st[ty * 8 + r][physW] = make_uint2(p0, p1);
        }
    }
    __syncthreads();                     // (4) S complete

    // ---- upper-tri tiles only: D = acc - S^T, packed write ----
    if (jo >= ty) {
        float sji[4][8];                 // sji[c][r] = S[j][i=ty*8+r]
        const int physR = (ty ^ (jo & 7)) * 8;
        #pragma unroll
        for (int c = 0; c < 4; ++c) {
            const int j = jo * 8 + jh * 4 + c;
            uint4 u = *(const uint4*)&sb.st[j][physR];
            unsigned int xs[4] = {u.x, u.y, u.z, u.w};
            #pragma unroll
            for (int k = 0; k < 4; ++k) {
                sji[c][2*k]   = bf2f(xs[k] & 0xffff);
                sji[c][2*k+1] = bf2f(xs[k] >> 16);
            }
        }
        const int tidx = ty * 16 - (ty * (ty - 1)) / 2 + (jo - ty);
        unsigned short* Dn = Dp + (size_t)n * NSLAB + tidx * 64;
        #pragma unroll
        for (int r = 0; r < 8; ++r) {
            unsigned int p0 = cvtpk_bf16(acc[r][0] - sji[0][r],
                                         acc[r][1] - sji[1][r]);
            unsigned int p1 = cvtpk_bf16(acc[r][2] - sji[2][r],
                                         acc[r][3] - sji[3][r]);
            *(uint2*)&Dn[r * 8 + jh * 4] = make_uint2(p0, p1);
        }
    }
}

// ---------------------------------------------------------------------------
// K3: one block per packed tile (grid 136, 256 thr). Reads its tile for all
// 256 n (uint4, coalesced), reduces in LDS, then each valid cell (j>i)
// emits A[i][j], A[j][i] = (1-sigma)*sigma(wm), and wm both orientations.
// ---------------------------------------------------------------------------
__global__ __launch_bounds__(256) void finalize_tiles(
    const unsigned short* __restrict__ Dp, const float* __restrict__ Wmag,
    float* __restrict__ out)
{
    __shared__ float red[32][72];        // 32 n-groups x 64 cells (+pad)

    const int b = blockIdx.x;            // 0..135
    int tq = 0, base = 0;                // invert b -> (tq, tp), uniform scalar
    while (b >= base + (16 - tq)) { base += 16 - tq; ++tq; }
    const int tp = tq + (b - base);

    const int t = threadIdx.x;
    const int g = t >> 3;                // n-group 0..31 (8 n each)
    const int s = t & 7;                 // tile row

    float a8[8] = {0.f, 0.f, 0.f, 0.f, 0.f, 0.f, 0.f, 0.f};
    #pragma unroll 2
    for (int q = 0; q < 8; ++q) {
        const int nn = g * 8 + q;
        uint4 u = *(const uint4*)&Dp[(size_t)nn * NSLAB + b * 64 + s * 8];
        unsigned int xs[4] = {u.x, u.y, u.z, u.w};
        #pragma unroll
        for (int k = 0; k < 4; ++k) {
            a8[2*k]   += bf2f(xs[k] & 0xffff);
            a8[2*k+1] += bf2f(xs[k] >> 16);
        }
    }
    *(float4*)&red[g][s * 8]     = make_float4(a8[0], a8[1], a8[2], a8[3]);
    *(float4*)&red[g][s * 8 + 4] = make_float4(a8[4], a8[5], a8[6], a8[7]);
    __syncthreads();

    if (t < 64) {
        const int r = t >> 3, c = t & 7;
        float sum = 0.f;
        #pragma unroll 8
        for (int gg = 0; gg < 32; ++gg) sum += red[gg][t];

        const int i = 8 * tq + r;
        const int j = 8 * tp + c;
        if (i == j) {                    // diag cell: owned once (tq==tp, r==c)
            out[i * D + i]         = 0.f;
            out[D * D + i * D + i] = 0.f;
        } else if (j > i) {              // valid cell (all cells if tp>tq)
            float av  = sum * (1.0f / 256.0f);        // mean over n; TAU = 1
            float dir = 1.0f / (1.0f + __expf(-av));
            float wmm = 0.5f * (Wmag[i * D + j] + Wmag[j * D + i]);
            float sw  = 1.0f / (1.0f + __expf(-wmm));
            out[i * D + j]         = dir * sw;          // A[i][j]
            out[j * D + i]         = (1.0f - dir) * sw; // A[j][i] = sigma(-av)*sw
            out[D * D + i * D + j] = wmm;
            out[D * D + j * D + i] = wmm;
        }
        // cells j < i in diag tiles: mirrored by their (c,r) counterpart
    }
}

extern "C" void kernel_launch(void* const* d_in, const int* in_sizes, int n_in,
                              void* d_out, int out_size, void* d_ws, size_t ws_size,
                              hipStream_t stream)
{
    const float* z    = (const float*)d_in[0];   // (4,64,128,32)
    const float* Wmag = (const float*)d_in[1];   // (128,128)
    const float* W1   = (const float*)d_in[2];   // (32,64)
    const float* b1   = (const float*)d_in[3];   // (32,)
    const float* W2   = (const float*)d_in[4];   // (1,32)
    // d_in[5] = b2: cancels in scores - scores^T.

    unsigned short* Dp = (unsigned short*)d_ws;  // packed upper-tri D, 4.35 MB
    float* out = (float*)d_out;

    fused_pab_scores<<<NT, 512, 0, stream>>>(z, W1, b1, W2, Dp);
    finalize_tiles<<<TILES, 256, 0, stream>>>(Dp, Wmag, out);
}

// Round 18
// 24.383 us; speedup vs baseline: 1.2355x; 1.0341x over previous
//
#include <hip/hip_runtime.h>
#include <hip/hip_bf16.h>
#include <math.h>

#define D     128
#define NT    256            // B*T
#define HD    32
#define LD    32
#define P32   132            // u32-row pad for fp16-pair tiles
#define STW   136            // st row stride in u16 (272 B, 16B-aligned)
#define TILES 136            // 16*17/2 upper-incl-diag 8x8 tiles
#define NSLAB (TILES * 64)   // u16 per token in packed D

typedef _Float16 h2v __attribute__((ext_vector_type(2)));

static __device__ inline float bf2f(unsigned int u16v) {
    union { unsigned int i; float f; } v;
    v.i = u16v << 16;
    return v.f;
}
// RNE fp16 pair pack; only outside hot loops
static __device__ inline unsigned int pkh2(float a, float b) {
    union { h2v h; unsigned int u; } cv;
    cv.h = (h2v){(_Float16)a, (_Float16)b};
    return cv.u;
}
static __device__ inline h2v u2h(unsigned int u) {
    union { unsigned int u; h2v h; } cv; cv.u = u; return cv.h;
}
static __device__ inline float fdot2f(h2v a, h2v b, float c) {
#if __has_builtin(__builtin_amdgcn_fdot2)
    return __builtin_amdgcn_fdot2(a, b, c, false);
#else
    return c + (float)a[0] * (float)b[0] + (float)a[1] * (float)b[1];
#endif
}
// 2x f32 -> packed bf16 pair (RNE), single instruction on gfx950
static __device__ inline unsigned int cvtpk_bf16(float lo, float hi) {
    unsigned int r;
    asm("v_cvt_pk_bf16_f32 %0, %1, %2" : "=v"(r) : "v"(lo), "v"(hi));
    return r;
}

union SmemA {                        // staging (P1) overlaid with lin (P2+)
    struct {
        unsigned int zt[16][P32];    // fp16 l-pairs of z, transposed: 8.4 KB
        unsigned int w1pk[32][36];   // fp16 l-pairs of W1 rows: 4.6 KB
        unsigned int w2p[16];        // fp16 h-pairs of w2/2: 64 B
    } s;
    float lin[2][D];                 // rank-1 relu-split terms, 1 KB
};
union SmemB {                        // fp16-pair pa/pb overlaid with st buf
    struct { unsigned int a[16][P32]; unsigned int b[16][P32]; } p;  // 16.9 KB
    unsigned short st[D][STW];                                       // 34.8 KB
};

// ---------------------------------------------------------------------------
// K12: one block per token n, 512 threads (same structure as R17 — P3 is at
// its instruction floor: pk_add + and(|.|x2) + fdot2 = 3 VALU per 2h/cell).
// ---------------------------------------------------------------------------
__global__ __launch_bounds__(512) void fused_pab_scores(
    const float* __restrict__ z, const float* __restrict__ W1,
    const float* __restrict__ b1, const float* __restrict__ W2,
    unsigned short* __restrict__ Dp)
{
    __shared__ SmemA sa;
    __shared__ SmemB sb;

    const int t = threadIdx.x;
    const int n = blockIdx.x;

    // ---- stage z transposed as fp16 l-pairs: 1024 float4, 2/thread ----
    {
        const float4* zsrc = (const float4*)(z + (size_t)n * (D * LD));
        #pragma unroll
        for (int q = 0; q < 2; ++q) {
            int f = t + q * 512;
            float4 v = zsrc[f];
            int i  = f >> 3;             // 0..127
            int l2 = (f & 7) * 2;        // l-pair index
            sa.s.zt[l2][i]     = pkh2(v.x, v.y);
            sa.s.zt[l2 + 1][i] = pkh2(v.z, v.w);
        }
    }
    // ---- stage W1 packed cooperatively: 1024 u32, 2/thread ----
    {
        #pragma unroll
        for (int q = 0; q < 2; ++q) {
            int u = t + q * 512;         // 0..1023
            float2 w = *(const float2*)&W1[2 * u];
            sa.s.w1pk[u >> 5][u & 31] = pkh2(w.x, w.y);
        }
    }
    if (t < 16)
        sa.s.w2p[t] = pkh2(0.5f * W2[2 * t], 0.5f * W2[2 * t + 1]);

    const int h2i = t & 15;              // h-pair 0..15
    const int iq  = t >> 4;              // i-quad 0..31
    const int h0 = 2 * h2i, h1 = h0 + 1;
    const float bias0 = b1[h0], bias1 = b1[h1];
    __syncthreads();                     // (1) z/W1/w2 staged

    // ---- read back packed W1 rows + w2 (b128 batches) ----
    unsigned int wpkA0[16], wpkA1[16], wpkB0[16], wpkB1[16], w2pk[16];
    #pragma unroll
    for (int k = 0; k < 4; ++k) {
        *(uint4*)&wpkA0[4*k] = *(const uint4*)&sa.s.w1pk[h0][4*k];
        *(uint4*)&wpkB0[4*k] = *(const uint4*)&sa.s.w1pk[h0][16 + 4*k];
        *(uint4*)&wpkA1[4*k] = *(const uint4*)&sa.s.w1pk[h1][4*k];
        *(uint4*)&wpkB1[4*k] = *(const uint4*)&sa.s.w1pk[h1][16 + 4*k];
        *(uint4*)&w2pk[4*k]  = *(const uint4*)&sa.s.w2p[4*k];
    }

    // ---- P1: 4 i's x (h0,h1) x (a,b) = 16 f32 accs over 16 fdot2 ----
    {
        float A0[4], A1[4], B0[4], B1[4];
        #pragma unroll
        for (int r = 0; r < 4; ++r) { A0[r] = bias0; A1[r] = bias1; B0[r] = 0.f; B1[r] = 0.f; }
        #pragma unroll
        for (int l2 = 0; l2 < 16; ++l2) {
            unsigned int zq[4];
            *(uint4*)zq = *(const uint4*)&sa.s.zt[l2][iq * 4];
            #pragma unroll
            for (int r = 0; r < 4; ++r) {
                h2v zv = u2h(zq[r]);
                A0[r] = fdot2f(zv, u2h(wpkA0[l2]), A0[r]);
                A1[r] = fdot2f(zv, u2h(wpkA1[l2]), A1[r]);
                B0[r] = fdot2f(zv, u2h(wpkB0[l2]), B0[r]);
                B1[r] = fdot2f(zv, u2h(wpkB1[l2]), B1[r]);
            }
        }
        unsigned int pa4[4], pb4[4];
        #pragma unroll
        for (int r = 0; r < 4; ++r) {
            pa4[r] = pkh2(A0[r], A1[r]);     // pack across h-pair
            pb4[r] = pkh2(B0[r], B1[r]);
        }
        *(uint4*)&sb.p.a[h2i][iq * 4] = *(uint4*)pa4;
        *(uint4*)&sb.p.b[h2i][iq * 4] = *(uint4*)pb4;
    }
    __syncthreads();                     // (2) fp16 pa/pb ready; staging dead

    // ---- P2 (t<256; overlaps P3, joined at barrier (3)) ----
    if (t < 256) {
        const int kind = t >> 7, i2 = t & 127;
        float s = 0.f;
        #pragma unroll
        for (int q = 0; q < 16; ++q) {
            unsigned int v = kind ? sb.p.b[q][i2] : sb.p.a[q][i2];
            s = fdot2f(u2h(v), u2h(w2pk[q]), s);
        }
        sa.lin[kind][i2] = s;            // consumed after barrier (3)
    }

    // ---- P3: abs part, 8i x 4j per thread, fp16-pair datapath ----
    const int tx = t & 31;               // j-quad
    const int ty = t >> 5;               // i-oct
    float acc[8][4];
    #pragma unroll
    for (int r = 0; r < 8; ++r)
        #pragma unroll
        for (int c = 0; c < 4; ++c) acc[r][c] = 0.f;

    #pragma unroll 4
    for (int q = 0; q < 16; ++q) {
        unsigned int a8[8], b4[4];
        *(uint4*)&a8[0] = *(const uint4*)&sb.p.a[q][ty * 8];
        *(uint4*)&a8[4] = *(const uint4*)&sb.p.a[q][ty * 8 + 4];
        *(uint4*)&b4[0] = *(const uint4*)&sb.p.b[q][tx * 4];
        const h2v w = u2h(w2pk[q]);
        #pragma unroll
        for (int r = 0; r < 8; ++r) {
            const h2v ha = u2h(a8[r]);
            #pragma unroll
            for (int c = 0; c < 4; ++c) {
                union { h2v h; unsigned int u; } cv;
                cv.h = ha + u2h(b4[c]);              // v_pk_add_f16
                cv.u &= 0x7fff7fffu;                 // |.| both halves
                acc[r][c] = fdot2f(cv.h, w, acc[r][c]);
            }
        }
    }
    __syncthreads();                     // (3) P3/P2 reads done; lin visible

    // ---- add linear terms ----
    {
        float cai[8], cbj[4];
        #pragma unroll
        for (int r = 0; r < 8; ++r) cai[r] = sa.lin[0][ty * 8 + r];
        #pragma unroll
        for (int c = 0; c < 4; ++c) cbj[c] = sa.lin[1][tx * 4 + c];
        #pragma unroll
        for (int r = 0; r < 8; ++r)
            #pragma unroll
            for (int c = 0; c < 4; ++c)
                acc[r][c] += cai[r] + cbj[c];
    }

    // ---- S -> st (bf16 via cvt_pk, XOR oct-swizzled) ----
    const int jo = tx >> 1;              // j-oct 0..15
    const int jh = tx & 1;               // half within oct
    {
        const int physW = ((jo ^ (ty & 7)) * 8) + jh * 4;
        #pragma unroll
        for (int r = 0; r < 8; ++r) {
            unsigned int p0 = cvtpk_bf16(acc[r][0], acc[r][1]);
            unsigned int p1 = cvtpk_bf16(acc[r][2], acc[r][3]);
            *(uint2*)&sb.st[ty * 8 + r][physW] = make_uint2(p0, p1);
        }
    }
    __syncthreads();                     // (4) S complete

    // ---- upper-tri tiles only: D = acc - S^T, packed write ----
    if (jo >= ty) {
        float sji[4][8];                 // sji[c][r] = S[j][i=ty*8+r]
        const int physR = (ty ^ (jo & 7)) * 8;
        #pragma unroll
        for (int c = 0; c < 4; ++c) {
            const int j = jo * 8 + jh * 4 + c;
            uint4 u = *(const uint4*)&sb.st[j][physR];
            unsigned int xs[4] = {u.x, u.y, u.z, u.w};
            #pragma unroll
            for (int k = 0; k < 4; ++k) {
                sji[c][2*k]   = bf2f(xs[k] & 0xffff);
                sji[c][2*k+1] = bf2f(xs[k] >> 16);
            }
        }
        const int tidx = ty * 16 - (ty * (ty - 1)) / 2 + (jo - ty);
        unsigned short* Dn = Dp + (size_t)n * NSLAB + tidx * 64;
        #pragma unroll
        for (int r = 0; r < 8; ++r) {
            unsigned int p0 = cvtpk_bf16(acc[r][0] - sji[0][r],
                                         acc[r][1] - sji[1][r]);
            unsigned int p1 = cvtpk_bf16(acc[r][2] - sji[2][r],
                                         acc[r][3] - sji[3][r]);
            *(uint2*)&Dn[r * 8 + jh * 4] = make_uint2(p0, p1);
        }
    }
}

// ---------------------------------------------------------------------------
// K3: one block per packed tile, 512 threads (was 256): 4 uint4 loads per
// thread (half the serial load depth), 64-group two-stage LDS reduce.
// ---------------------------------------------------------------------------
__global__ __launch_bounds__(512) void finalize_tiles(
    const unsigned short* __restrict__ Dp, const float* __restrict__ Wmag,
    float* __restrict__ out)
{
    __shared__ float red[64][72];        // 64 n-groups x 64 cells (+pad), 18.4 KB
    __shared__ float red2[8][72];        // second stage

    const int b = blockIdx.x;            // 0..135
    int tq = 0, base = 0;                // invert b -> (tq, tp), uniform scalar
    while (b >= base + (16 - tq)) { base += 16 - tq; ++tq; }
    const int tp = tq + (b - base);

    const int t = threadIdx.x;
    const int g = t >> 3;                // n-group 0..63 (4 n each)
    const int s = t & 7;                 // tile row

    float a8[8] = {0.f, 0.f, 0.f, 0.f, 0.f, 0.f, 0.f, 0.f};
    #pragma unroll
    for (int q = 0; q < 4; ++q) {
        const int nn = g * 4 + q;
        uint4 u = *(const uint4*)&Dp[(size_t)nn * NSLAB + b * 64 + s * 8];
        unsigned int xs[4] = {u.x, u.y, u.z, u.w};
        #pragma unroll
        for (int k = 0; k < 4; ++k) {
            a8[2*k]   += bf2f(xs[k] & 0xffff);
            a8[2*k+1] += bf2f(xs[k] >> 16);
        }
    }
    *(float4*)&red[g][s * 8]     = make_float4(a8[0], a8[1], a8[2], a8[3]);
    *(float4*)&red[g][s * 8 + 4] = make_float4(a8[4], a8[5], a8[6], a8[7]);
    __syncthreads();

    // stage 2: 512 threads: cell (t&63), 8-group slice (t>>6)
    {
        const int cell = t & 63, sl = t >> 6;
        float s2 = 0.f;
        #pragma unroll
        for (int k = 0; k < 8; ++k) s2 += red[sl * 8 + k][cell];
        red2[sl][cell] = s2;
    }
    __syncthreads();

    if (t < 64) {
        const int r = t >> 3, c = t & 7;
        float sum = red2[0][t] + red2[1][t] + red2[2][t] + red2[3][t]
                  + red2[4][t] + red2[5][t] + red2[6][t] + red2[7][t];

        const int i = 8 * tq + r;
        const int j = 8 * tp + c;
        if (i == j) {                    // diag cell: owned once (tq==tp, r==c)
            out[i * D + i]         = 0.f;
            out[D * D + i * D + i] = 0.f;
        } else if (j > i) {              // valid cell (all cells if tp>tq)
            float av  = sum * (1.0f / 256.0f);        // mean over n; TAU = 1
            float dir = 1.0f / (1.0f + __expf(-av));
            float wmm = 0.5f * (Wmag[i * D + j] + Wmag[j * D + i]);
            float sw  = 1.0f / (1.0f + __expf(-wmm));
            out[i * D + j]         = dir * sw;          // A[i][j]
            out[j * D + i]         = (1.0f - dir) * sw; // A[j][i] = sigma(-av)*sw
            out[D * D + i * D + j] = wmm;
            out[D * D + j * D + i] = wmm;
        }
        // cells j < i in diag tiles: mirrored by their (c,r) counterpart
    }
}

extern "C" void kernel_launch(void* const* d_in, const int* in_sizes, int n_in,
                              void* d_out, int out_size, void* d_ws, size_t ws_size,
                              hipStream_t stream)
{
    const float* z    = (const float*)d_in[0];   // (4,64,128,32)
    const float* Wmag = (const float*)d_in[1];   // (128,128)
    const float* W1   = (const float*)d_in[2];   // (32,64)
    const float* b1   = (const float*)d_in[3];   // (32,)
    const float* W2   = (const float*)d_in[4];   // (1,32)
    // d_in[5] = b2: cancels in scores - scores^T.

    unsigned short* Dp = (unsigned short*)d_ws;  // packed upper-tri D, 4.35 MB
    float* out = (float*)d_out;

    fused_pab_scores<<<NT, 512, 0, stream>>>(z, W1, b1, W2, Dp);
    finalize_tiles<<<TILES, 512, 0, stream>>>(Dp, Wmag, out);
}